// Round 8
// baseline (37.123 us; speedup 1.0000x reference)
//
#include <hip/hip_runtime.h>

// Algebraic collapse (verified exactly, absmax 0.0 across rounds):
//   softmax over the QUERY axis => sum_q attn[b,q,k] == 1 for all (b,k), so
//   context.mean(axis=0) = mean_k V[k,b,:] = xbar @ Wv.T + bv, and
//   out[b,h] = xbar[b,h] + sum_j xbar[b,j]*Wv[h,j] + bv[h],  xbar = x.mean(0).
//   Wq, bq, Wk, bk drop out of the output entirely.
// Lessons:
//   R2: NO cooperative grid.sync on MI355X (~100us/sync). Plain boundaries.
//   R3-R6 colsum scan at fixed 4KB-run shape: 1024 blk=38.4, 512 blk=25.2
//     (BEST), 256 blk=26.4 => 512 blocks / 8 waves/CU frozen.
//   R7: k_out wave-per-(h,8b) Wv-register-reuse: 25.2 -> 23.9. FROZEN.
//   R8 experiment (single variable): colsum run length 4KB -> 8KB per block
//     at the same 512 blocks: grid (16,32) -> (8,64), 2 float4/row/thread.
//     Tests HBM channel-spread theory. k_out byte-identical to R7.

constexpr int S = 1024;
constexpr int B = 16;
constexpr int H = 1024;
constexpr int C = B * H;            // 16384 columns when x is viewed [S][B*H]
constexpr int C4 = C / 4;           // 4096 float4 columns
constexpr int CHUNKS = 8;           // column chunks (8 KB each)
constexpr int CW = C4 / CHUNKS;     // 512 float4 per chunk
constexpr int SPLITS = 64;          // S-axis splits -> 8*64 = 512 blocks
constexpr int SCHUNK = S / SPLITS;  // 16 rows per block

// --- K1: partial column sums. grid (8, 64) = 512 blocks, block 256.
// Each thread: 2 float4 columns, 16 rows => 32 independent loads in flight.
__global__ void __launch_bounds__(256) k_colsum(const float4* __restrict__ x4,
                                                float4* __restrict__ part4) {
    const int t  = threadIdx.x;
    const int bx = blockIdx.x;      // [0, 8)
    const int y  = blockIdx.y;      // [0, 64)
    const int c0 = bx * CW + t;     // first float4 column
    const float4* p = x4 + (size_t)y * SCHUNK * C4 + c0;
    float4 a0 = make_float4(0.f, 0.f, 0.f, 0.f);
    float4 a1 = make_float4(0.f, 0.f, 0.f, 0.f);
#pragma unroll
    for (int i = 0; i < SCHUNK; ++i) {
        float4 v0 = p[(size_t)i * C4];
        float4 v1 = p[(size_t)i * C4 + 256];
        a0.x += v0.x; a0.y += v0.y; a0.z += v0.z; a0.w += v0.w;
        a1.x += v1.x; a1.y += v1.y; a1.z += v1.z; a1.w += v1.w;
    }
    part4[(size_t)y * C4 + c0]       = a0;
    part4[(size_t)y * C4 + c0 + 256] = a1;
}

// --- K1.5: fold 64 partial rows -> xsum[C]. 64 blocks, coalesced.
__global__ void __launch_bounds__(256) k_reduce(const float* __restrict__ part,
                                                float* __restrict__ xsum) {
    const int c = blockIdx.x * blockDim.x + threadIdx.x;
    float a = 0.f;
#pragma unroll
    for (int t = 0; t < SPLITS; ++t) a += part[(size_t)t * C + c];
    xsum[c] = a;
}

// --- K2 (R7-frozen): one wave per (h, b-octet). 512 blocks x 256 = 2048 waves.
__global__ void __launch_bounds__(256) k_out(const float* __restrict__ xsum,
                                             const float* __restrict__ Wv,
                                             const float* __restrict__ bv,
                                             float* __restrict__ out) {
    const int wid  = (blockIdx.x * 256 + threadIdx.x) >> 6;  // [0, 2048)
    const int lane = threadIdx.x & 63;
    const int h    = wid >> 1;           // [0, 1024)
    const int bh   = (wid & 1) * 8;      // 0 or 8

    const float4* wr = (const float4*)(Wv + (size_t)h * H);  // 256 float4/row
    const float4 w0 = wr[lane], w1 = wr[lane + 64],
                 w2 = wr[lane + 128], w3 = wr[lane + 192];
    const float bvh = bv[h];

    float acc[8];
#pragma unroll
    for (int b = 0; b < 8; ++b) {
        const float4* xr = (const float4*)(xsum + (size_t)(bh + b) * H);
        const float4 a0 = xr[lane], a1 = xr[lane + 64],
                     a2 = xr[lane + 128], a3 = xr[lane + 192];
        acc[b] = a0.x * w0.x + a0.y * w0.y + a0.z * w0.z + a0.w * w0.w
               + a1.x * w1.x + a1.y * w1.y + a1.z * w1.z + a1.w * w1.w
               + a2.x * w2.x + a2.y * w2.y + a2.z * w2.z + a2.w * w2.w
               + a3.x * w3.x + a3.y * w3.y + a3.z * w3.z + a3.w * w3.w;
    }
#pragma unroll
    for (int b = 0; b < 8; ++b) {
#pragma unroll
        for (int off = 32; off; off >>= 1) acc[b] += __shfl_down(acc[b], off, 64);
    }
    if (lane == 0) {
#pragma unroll
        for (int b = 0; b < 8; ++b) {
            const int c = (bh + b) * H + h;
            out[c] = (xsum[c] + acc[b]) * (1.0f / (float)S) + bvh;
        }
    }
}

extern "C" void kernel_launch(void* const* d_in, const int* in_sizes, int n_in,
                              void* d_out, int out_size, void* d_ws, size_t ws_size,
                              hipStream_t stream) {
    const float* x  = (const float*)d_in[0];
    // d_in[1..4] (Wq,bq,Wk,bk) are provably unused (see header).
    const float* Wv = (const float*)d_in[5];
    const float* bv = (const float*)d_in[6];
    float* out = (float*)d_out;
    float* ws  = (float*)d_ws;

    float* part = ws;                       // [SPLITS][C]  = 4 MiB
    float* xsum = ws + (size_t)SPLITS * C;  // [C]
    k_colsum<<<dim3(CHUNKS, SPLITS), 256, 0, stream>>>(
        (const float4*)x, (float4*)part);
    k_reduce<<<C / 256, 256, 0, stream>>>(part, xsum);
    k_out<<<512, 256, 0, stream>>>(xsum, Wv, bv, out);
}

// Round 9
// 36.519 us; speedup vs baseline: 1.0165x; 1.0165x over previous
//
#include <hip/hip_runtime.h>

// Algebraic collapse (verified exactly, absmax 0.0 across rounds):
//   softmax over the QUERY axis => sum_q attn[b,q,k] == 1 for all (b,k), so
//   context.mean(axis=0) = mean_k V[k,b,:] = xbar @ Wv.T + bv, and
//   out[b,h] = xbar[b,h] + sum_j xbar[b,j]*Wv[h,j] + bv[h],  xbar = x.mean(0).
//   Wq, bq, Wk, bk drop out of the output entirely.
// Lessons:
//   R2: NO cooperative grid.sync on MI355X (~100us/sync).
//   R3-R8 strided-colsum scan: best 25.2us (512 blk, SCHUNK=32, 4KB runs);
//     SCHUNK=16 configs catastrophically bad (37-38us) regardless of block
//     count/run width. Strided-64KB column sums have opaque DRAM behavior —
//     stop tuning within that class.
//   R7: k_out wave-per-(h,8b) Wv-register-reuse. FROZEN (best total 23.9us).
//   R9: colsum pattern class change -> fully CONTIGUOUS x reads: block owns
//     4 contiguous rows (256KB linear span), 1024 thr, 4 f4 accumulators.
//     part grows to 16MB (linear write; fold reads it from L3).

constexpr int S = 1024, B = 16, H = 1024;
constexpr int C  = B * H;         // 16384 floats per x row
constexpr int C4 = C / 4;         // 4096 float4 per row
constexpr int SPLITS = 256;       // blocks; 4 contiguous rows each
constexpr int RPB = S / SPLITS;   // 4 rows per block
constexpr int NTC = 1024;         // colsum block size (16 waves)

// ---- K1: contiguous-read column partial sums.
// grid 256, block 1024. Block y reads rows [4y,4y+4) linearly (256KB span).
__global__ void __launch_bounds__(NTC) k_colsum(const float4* __restrict__ x4,
                                                float4* __restrict__ part4) {
    const int t = threadIdx.x;
    const int y = blockIdx.x;                    // [0,256)
    const float4* p = x4 + (size_t)y * RPB * C4;
    float4 a0 = make_float4(0.f,0.f,0.f,0.f), a1 = a0, a2 = a0, a3 = a0;
#pragma unroll
    for (int r = 0; r < RPB; ++r) {
        const float4* row = p + (size_t)r * C4;
        float4 v0 = row[t];
        float4 v1 = row[t + NTC];
        float4 v2 = row[t + 2 * NTC];
        float4 v3 = row[t + 3 * NTC];
        a0.x+=v0.x; a0.y+=v0.y; a0.z+=v0.z; a0.w+=v0.w;
        a1.x+=v1.x; a1.y+=v1.y; a1.z+=v1.z; a1.w+=v1.w;
        a2.x+=v2.x; a2.y+=v2.y; a2.z+=v2.z; a2.w+=v2.w;
        a3.x+=v3.x; a3.y+=v3.y; a3.z+=v3.z; a3.w+=v3.w;
    }
    float4* q = part4 + (size_t)y * C4;
    q[t]           = a0;
    q[t + NTC]     = a1;
    q[t + 2 * NTC] = a2;
    q[t + 3 * NTC] = a3;
}

// ---- K2: fold 256 partial rows -> xsum[C]. 64 blocks x 256 thr.
// 4 independent 64-deep accumulation streams per thread; part is L3-resident.
__global__ void __launch_bounds__(256) k_fold(const float* __restrict__ part,
                                              float* __restrict__ xsum) {
    const int c = blockIdx.x * 256 + threadIdx.x;   // [0, 16384)
    float s0 = 0.f, s1 = 0.f, s2 = 0.f, s3 = 0.f;
#pragma unroll 8
    for (int y = 0; y < 64; ++y) {
        s0 += part[(size_t)y         * C + c];
        s1 += part[(size_t)(y + 64)  * C + c];
        s2 += part[(size_t)(y + 128) * C + c];
        s3 += part[(size_t)(y + 192) * C + c];
    }
    xsum[c] = (s0 + s1) + (s2 + s3);
}

// ---- K3 (R7-frozen): one wave per (h, b-octet). 512 blocks x 256 thr.
__global__ void __launch_bounds__(256) k_out(const float* __restrict__ xsum,
                                             const float* __restrict__ Wv,
                                             const float* __restrict__ bv,
                                             float* __restrict__ out) {
    const int wid  = (blockIdx.x * 256 + threadIdx.x) >> 6;  // [0, 2048)
    const int lane = threadIdx.x & 63;
    const int h    = wid >> 1;           // [0, 1024)
    const int bh   = (wid & 1) * 8;      // 0 or 8

    const float4* wr = (const float4*)(Wv + (size_t)h * H);  // 256 float4/row
    const float4 w0 = wr[lane], w1 = wr[lane + 64],
                 w2 = wr[lane + 128], w3 = wr[lane + 192];
    const float bvh = bv[h];

    float acc[8];
#pragma unroll
    for (int b = 0; b < 8; ++b) {
        const float4* xr = (const float4*)(xsum + (size_t)(bh + b) * H);
        const float4 a0 = xr[lane], a1 = xr[lane + 64],
                     a2 = xr[lane + 128], a3 = xr[lane + 192];
        acc[b] = a0.x * w0.x + a0.y * w0.y + a0.z * w0.z + a0.w * w0.w
               + a1.x * w1.x + a1.y * w1.y + a1.z * w1.z + a1.w * w1.w
               + a2.x * w2.x + a2.y * w2.y + a2.z * w2.z + a2.w * w2.w
               + a3.x * w3.x + a3.y * w3.y + a3.z * w3.z + a3.w * w3.w;
    }
#pragma unroll
    for (int b = 0; b < 8; ++b) {
#pragma unroll
        for (int off = 32; off; off >>= 1) acc[b] += __shfl_down(acc[b], off, 64);
    }
    if (lane == 0) {
#pragma unroll
        for (int b = 0; b < 8; ++b) {
            const int c = (bh + b) * H + h;
            out[c] = (xsum[c] + acc[b]) * (1.0f / (float)S) + bvh;
        }
    }
}

// ---- Fallback (exact R7 path) if ws is too small for the 16MB part. ----
constexpr int FSPLITS = 32, FSCHUNK = S / FSPLITS;
__global__ void k_colsum_f(const float4* __restrict__ x4, float4* __restrict__ part4) {
    const int c4 = blockIdx.x * blockDim.x + threadIdx.x;
    const int split = blockIdx.y;
    const float4* p = x4 + (size_t)split * FSCHUNK * C4 + c4;
    float4 a = make_float4(0.f, 0.f, 0.f, 0.f);
#pragma unroll
    for (int i = 0; i < FSCHUNK; ++i) {
        float4 v = p[(size_t)i * C4];
        a.x += v.x; a.y += v.y; a.z += v.z; a.w += v.w;
    }
    part4[(size_t)split * C4 + c4] = a;
}
__global__ void k_fold_f(const float* __restrict__ part, float* __restrict__ xsum) {
    const int c = blockIdx.x * blockDim.x + threadIdx.x;
    float a = 0.f;
#pragma unroll
    for (int t = 0; t < FSPLITS; ++t) a += part[(size_t)t * C + c];
    xsum[c] = a;
}

extern "C" void kernel_launch(void* const* d_in, const int* in_sizes, int n_in,
                              void* d_out, int out_size, void* d_ws, size_t ws_size,
                              hipStream_t stream) {
    const float* x  = (const float*)d_in[0];
    // d_in[1..4] (Wq,bq,Wk,bk) are provably unused (see header).
    const float* Wv = (const float*)d_in[5];
    const float* bv = (const float*)d_in[6];
    float* out = (float*)d_out;
    float* ws  = (float*)d_ws;

    const size_t need = (size_t)(SPLITS + 1) * C * sizeof(float);  // ~16.06 MiB
    if (ws_size >= need) {
        float* part = ws;                        // [256][C] = 16 MiB
        float* xsum = ws + (size_t)SPLITS * C;   // [C]
        k_colsum<<<SPLITS, NTC, 0, stream>>>((const float4*)x, (float4*)part);
        k_fold<<<C / 256, 256, 0, stream>>>(part, xsum);
        k_out<<<512, 256, 0, stream>>>(xsum, Wv, bv, out);
    } else {
        float* part = ws;                        // [32][C] = 2 MiB
        float* xsum = ws + (size_t)FSPLITS * C;  // [C]
        k_colsum_f<<<dim3(C4 / 256, FSPLITS), 256, 0, stream>>>(
            (const float4*)x, (float4*)part);
        k_fold_f<<<C / 256, 256, 0, stream>>>(part, xsum);
        k_out<<<512, 256, 0, stream>>>(xsum, Wv, bv, out);
    }
}

// Round 10
// 26.927 us; speedup vs baseline: 1.3786x; 1.3562x over previous
//
#include <hip/hip_runtime.h>

// Algebraic collapse (verified exactly, absmax 0.0 across rounds):
//   softmax over the QUERY axis => sum_q attn[b,q,k] == 1 for all (b,k), so
//   context.mean(axis=0) = mean_k V[k,b,:] = xbar @ Wv.T + bv, and
//   out[b,h] = xbar[b,h] + sum_j xbar[b,j]*Wv[h,j] + bv[h],  xbar = x.mean(0).
//   Wq, bq, Wk, bk drop out of the output entirely.
// Lessons:
//   R2: NO cooperative grid.sync on MI355X (~100us/sync).
//   R3-R9 colsum scan: good iff {SCHUNK>=32 AND part<=2MiB}: 23.9-26.4us.
//     All configs with part>=4MiB (or SCHUNK<=16) cost ~+12.5us FLAT,
//     including a fully CONTIGUOUS x-read (R9: 36.5). DRAM-side mechanism
//     opaque; law frozen: SCHUNK=32, part=2MiB.
//   R7: k_out wave-per-(h,8b) Wv-register-reuse. FROZEN. Best total 23.9us.
//   R10 probe (single variable, last colsum probe): run width 4KB->8KB at
//     good depth: grid (16,32)x256thr -> (8,32)x512thr. Same 2048 waves,
//     same per-column add order (absmax 0.0). fold/k_out byte-identical.

constexpr int S = 1024;
constexpr int B = 16;
constexpr int H = 1024;
constexpr int C = B * H;            // 16384 columns when x is viewed [S][B*H]
constexpr int C4 = C / 4;           // 4096 float4 columns
constexpr int SPLITS = 32;          // S-axis split (frozen good value)
constexpr int SCHUNK = S / SPLITS;  // 32 rows per block
constexpr int NTC = 512;            // colsum block threads (8 waves)

// --- K1: partial column sums. grid (8, 32) = 256 blocks, block 512.
// Each block: 8KB-wide strip x 32 rows; thread = one float4 column, 32-deep.
__global__ void __launch_bounds__(NTC) k_colsum(const float4* __restrict__ x4,
                                                float4* __restrict__ part4) {
    const int c4 = blockIdx.x * NTC + threadIdx.x;   // [0, 4096)
    const int split = blockIdx.y;
    const float4* p = x4 + (size_t)split * SCHUNK * C4 + c4;
    float4 a = make_float4(0.f, 0.f, 0.f, 0.f);
#pragma unroll
    for (int i = 0; i < SCHUNK; ++i) {
        float4 v = p[(size_t)i * C4];
        a.x += v.x; a.y += v.y; a.z += v.z; a.w += v.w;
    }
    part4[(size_t)split * C4 + c4] = a;
}

// --- K1.5 (R7 byte-identical): fold 32 partial rows -> xsum[C].
__global__ void k_reduce(const float* __restrict__ part, float* __restrict__ xsum) {
    const int c = blockIdx.x * blockDim.x + threadIdx.x;
    float a = 0.f;
#pragma unroll
    for (int t = 0; t < SPLITS; ++t) a += part[(size_t)t * C + c];
    xsum[c] = a;
}

// --- K2 (R7-frozen): one wave per (h, b-octet). 512 blocks x 256 = 2048 waves.
__global__ void __launch_bounds__(256) k_out(const float* __restrict__ xsum,
                                             const float* __restrict__ Wv,
                                             const float* __restrict__ bv,
                                             float* __restrict__ out) {
    const int wid  = (blockIdx.x * 256 + threadIdx.x) >> 6;  // [0, 2048)
    const int lane = threadIdx.x & 63;
    const int h    = wid >> 1;           // [0, 1024)
    const int bh   = (wid & 1) * 8;      // 0 or 8

    const float4* wr = (const float4*)(Wv + (size_t)h * H);  // 256 float4/row
    const float4 w0 = wr[lane], w1 = wr[lane + 64],
                 w2 = wr[lane + 128], w3 = wr[lane + 192];
    const float bvh = bv[h];

    float acc[8];
#pragma unroll
    for (int b = 0; b < 8; ++b) {
        const float4* xr = (const float4*)(xsum + (size_t)(bh + b) * H);
        const float4 a0 = xr[lane], a1 = xr[lane + 64],
                     a2 = xr[lane + 128], a3 = xr[lane + 192];
        acc[b] = a0.x * w0.x + a0.y * w0.y + a0.z * w0.z + a0.w * w0.w
               + a1.x * w1.x + a1.y * w1.y + a1.z * w1.z + a1.w * w1.w
               + a2.x * w2.x + a2.y * w2.y + a2.z * w2.z + a2.w * w2.w
               + a3.x * w3.x + a3.y * w3.y + a3.z * w3.z + a3.w * w3.w;
    }
#pragma unroll
    for (int b = 0; b < 8; ++b) {
#pragma unroll
        for (int off = 32; off; off >>= 1) acc[b] += __shfl_down(acc[b], off, 64);
    }
    if (lane == 0) {
#pragma unroll
        for (int b = 0; b < 8; ++b) {
            const int c = (bh + b) * H + h;
            out[c] = (xsum[c] + acc[b]) * (1.0f / (float)S) + bvh;
        }
    }
}

extern "C" void kernel_launch(void* const* d_in, const int* in_sizes, int n_in,
                              void* d_out, int out_size, void* d_ws, size_t ws_size,
                              hipStream_t stream) {
    const float* x  = (const float*)d_in[0];
    // d_in[1..4] (Wq,bq,Wk,bk) are provably unused (see header).
    const float* Wv = (const float*)d_in[5];
    const float* bv = (const float*)d_in[6];
    float* out = (float*)d_out;
    float* ws  = (float*)d_ws;

    float* part = ws;                       // [SPLITS][C]  = 2 MiB
    float* xsum = ws + (size_t)SPLITS * C;  // [C]
    k_colsum<<<dim3(C4 / NTC, SPLITS), NTC, 0, stream>>>(
        (const float4*)x, (float4*)part);
    k_reduce<<<C / 256, 256, 0, stream>>>(part, xsum);
    k_out<<<512, 256, 0, stream>>>(xsum, Wv, bv, out);
}

// Round 11
// 23.610 us; speedup vs baseline: 1.5723x; 1.1405x over previous
//
#include <hip/hip_runtime.h>

// Algebraic collapse (verified exactly, absmax 0.0 across rounds):
//   softmax over the QUERY axis => sum_q attn[b,q,k] == 1 for all (b,k), so
//   context.mean(axis=0) = mean_k V[k,b,:] = xbar @ Wv.T + bv, and
//   out[b,h] = xbar[b,h] + sum_j xbar[b,j]*Wv[h,j] + bv[h],  xbar = x.mean(0).
//   Wq, bq, Wk, bk drop out of the output entirely.
// Lessons:
//   R2: NO cooperative grid.sync on MI355X (~100us/sync).
//   R3-R10 colsum SHAPE scan closed: optimum = 512 blk / 4KB runs /
//     SCHUNK=32 / part=2MiB (23.9us). SCHUNK<=16 or part>=4MiB: +12us flat
//     (even fully-contiguous reads, R9). 8KB runs: +3us (R10). Shape probes
//     exhausted; landscape flat around optimum.
//   R7: k_out wave-per-(h,8b) Wv-register-reuse. FROZEN. Best total 23.9us.
//   R11 probe (single variable): NONTEMPORAL x loads (L2 no-allocate
//     streaming) on R7-exact geometry. x is 64MiB single-use: stop it from
//     thrashing the 32MiB L2 (keeps part resident for k_reduce).

constexpr int S = 1024;
constexpr int B = 16;
constexpr int H = 1024;
constexpr int C = B * H;            // 16384 columns when x is viewed [S][B*H]
constexpr int C4 = C / 4;           // 4096 float4 columns
constexpr int SPLITS = 32;          // S-axis split (frozen good value)
constexpr int SCHUNK = S / SPLITS;  // 32 rows per block

typedef float f4v __attribute__((ext_vector_type(4)));

// --- K1: partial column sums, R7 geometry, nontemporal x loads.
// grid (16, 32) = 512 blocks, block 256.
__global__ void __launch_bounds__(256) k_colsum(const f4v* __restrict__ x4,
                                                f4v* __restrict__ part4) {
    const int c4 = blockIdx.x * 256 + threadIdx.x;   // [0, 4096)
    const int split = blockIdx.y;
    const f4v* p = x4 + (size_t)split * SCHUNK * C4 + c4;
    f4v a = (f4v){0.f, 0.f, 0.f, 0.f};
#pragma unroll
    for (int i = 0; i < SCHUNK; ++i) {
        f4v v = __builtin_nontemporal_load(p + (size_t)i * C4);
        a += v;   // elementwise, same per-column add order as R7
    }
    part4[(size_t)split * C4 + c4] = a;
}

// --- K1.5 (R7 byte-identical): fold 32 partial rows -> xsum[C].
__global__ void k_reduce(const float* __restrict__ part, float* __restrict__ xsum) {
    const int c = blockIdx.x * blockDim.x + threadIdx.x;
    float a = 0.f;
#pragma unroll
    for (int t = 0; t < SPLITS; ++t) a += part[(size_t)t * C + c];
    xsum[c] = a;
}

// --- K2 (R7-frozen): one wave per (h, b-octet). 512 blocks x 256 = 2048 waves.
__global__ void __launch_bounds__(256) k_out(const float* __restrict__ xsum,
                                             const float* __restrict__ Wv,
                                             const float* __restrict__ bv,
                                             float* __restrict__ out) {
    const int wid  = (blockIdx.x * 256 + threadIdx.x) >> 6;  // [0, 2048)
    const int lane = threadIdx.x & 63;
    const int h    = wid >> 1;           // [0, 1024)
    const int bh   = (wid & 1) * 8;      // 0 or 8

    const float4* wr = (const float4*)(Wv + (size_t)h * H);  // 256 float4/row
    const float4 w0 = wr[lane], w1 = wr[lane + 64],
                 w2 = wr[lane + 128], w3 = wr[lane + 192];
    const float bvh = bv[h];

    float acc[8];
#pragma unroll
    for (int b = 0; b < 8; ++b) {
        const float4* xr = (const float4*)(xsum + (size_t)(bh + b) * H);
        const float4 a0 = xr[lane], a1 = xr[lane + 64],
                     a2 = xr[lane + 128], a3 = xr[lane + 192];
        acc[b] = a0.x * w0.x + a0.y * w0.y + a0.z * w0.z + a0.w * w0.w
               + a1.x * w1.x + a1.y * w1.y + a1.z * w1.z + a1.w * w1.w
               + a2.x * w2.x + a2.y * w2.y + a2.z * w2.z + a2.w * w2.w
               + a3.x * w3.x + a3.y * w3.y + a3.z * w3.z + a3.w * w3.w;
    }
#pragma unroll
    for (int b = 0; b < 8; ++b) {
#pragma unroll
        for (int off = 32; off; off >>= 1) acc[b] += __shfl_down(acc[b], off, 64);
    }
    if (lane == 0) {
#pragma unroll
        for (int b = 0; b < 8; ++b) {
            const int c = (bh + b) * H + h;
            out[c] = (xsum[c] + acc[b]) * (1.0f / (float)S) + bvh;
        }
    }
}

extern "C" void kernel_launch(void* const* d_in, const int* in_sizes, int n_in,
                              void* d_out, int out_size, void* d_ws, size_t ws_size,
                              hipStream_t stream) {
    const float* x  = (const float*)d_in[0];
    // d_in[1..4] (Wq,bq,Wk,bk) are provably unused (see header).
    const float* Wv = (const float*)d_in[5];
    const float* bv = (const float*)d_in[6];
    float* out = (float*)d_out;
    float* ws  = (float*)d_ws;

    float* part = ws;                       // [SPLITS][C]  = 2 MiB
    float* xsum = ws + (size_t)SPLITS * C;  // [C]
    k_colsum<<<dim3(C4 / 256, SPLITS), 256, 0, stream>>>(
        (const f4v*)x, (f4v*)part);
    k_reduce<<<C / 256, 256, 0, stream>>>(part, xsum);
    k_out<<<512, 256, 0, stream>>>(xsum, Wv, bv, out);
}